// Round 12
// baseline (38152.328 us; speedup 1.0000x reference)
//
#include <hip/hip_runtime.h>
#include <hip/hip_cooperative_groups.h>
#include <stdint.h>

namespace cg = cooperative_groups;

#define NDIM 4096
#define PD   128
#define TS   64
#define KC   64          // split-K chunk
#define LDK  (KC + 4)    // LDS row stride (68 floats: bank-skew 4)

// K = sigmoid(UA @ V^T - W): u8 K and K^T (loop) + optional fp32 K32 (plan).
// Round-8 proven: 114.8us @ 28.5% occupancy.
__global__ __launch_bounds__(256) void buildK_kernel(
    const float* __restrict__ UA, const float* __restrict__ V,
    const float* __restrict__ W, unsigned char* __restrict__ K8,
    unsigned char* __restrict__ KT8, float* __restrict__ K32)
{
    __shared__ float UAs[TS][LDK];
    __shared__ float Vs[TS][LDK];
    __shared__ float tileT[TS][TS + 1];
    const int i0 = blockIdx.y * TS, j0 = blockIdx.x * TS;
    const int t = threadIdx.x;
    const int tx = t & 15, ty = t >> 4;

    float acc[4][4] = {};
    for (int kc = 0; kc < PD; kc += KC) {
        for (int idx = t; idx < TS * (KC / 4); idx += 256) {
            const int r = idx >> 4;
            const int c = (idx & 15) << 2;
            *(float4*)&UAs[r][c] = *(const float4*)&UA[(size_t)(i0 + r) * PD + kc + c];
            *(float4*)&Vs[r][c]  = *(const float4*)&V[(size_t)(j0 + r) * PD + kc + c];
        }
        __syncthreads();
        for (int p = 0; p < KC; p += 4) {
            float4 a4[4], b4[4];
            #pragma unroll
            for (int ii = 0; ii < 4; ++ii) a4[ii] = *(const float4*)&UAs[ty + 16 * ii][p];
            #pragma unroll
            for (int jj = 0; jj < 4; ++jj) b4[jj] = *(const float4*)&Vs[tx + 16 * jj][p];
            #pragma unroll
            for (int ii = 0; ii < 4; ++ii)
                #pragma unroll
                for (int jj = 0; jj < 4; ++jj)
                    acc[ii][jj] += a4[ii].x * b4[jj].x + a4[ii].y * b4[jj].y
                                 + a4[ii].z * b4[jj].z + a4[ii].w * b4[jj].w;
        }
        __syncthreads();
    }

    #pragma unroll
    for (int ii = 0; ii < 4; ++ii) {
        const int i = ty + 16 * ii;
        #pragma unroll
        for (int jj = 0; jj < 4; ++jj) {
            const int j = tx + 16 * jj;
            const float w = W[(size_t)(i0 + i) * NDIM + (j0 + j)];
            tileT[j][i] = 1.0f / (1.0f + __expf(w - acc[ii][jj])); // sigmoid(UV - W)
        }
    }
    __syncthreads();
    // K^T u8, coalesced over i
    for (int idx = t; idx < TS * TS; idx += 256) {
        const int j = idx >> 6, i = idx & 63;
        KT8[(size_t)(j0 + j) * NDIM + (i0 + i)] = (unsigned char)(tileT[j][i] * 255.f + 0.5f);
    }
    // K u8 (+ optional fp32), coalesced over j
    for (int idx = t; idx < TS * TS; idx += 256) {
        const int i = idx >> 6, j = idx & 63;
        const float k = tileT[j][i];
        K8[(size_t)(i0 + i) * NDIM + (j0 + j)] = (unsigned char)(k * 255.f + 0.5f);
        if (K32) K32[(size_t)(i0 + i) * NDIM + (j0 + j)] = k;
    }
}

// UA[i][q] = sum_p U[i][p] * A[p][q]
__global__ __launch_bounds__(128) void ua_kernel(
    const float* __restrict__ U, const float* __restrict__ A, float* __restrict__ UA)
{
    __shared__ float us[PD];
    const int i = blockIdx.x;
    const int q = threadIdx.x;
    us[q] = U[i * PD + q];
    __syncthreads();
    float acc = 0.f;
    #pragma unroll 8
    for (int p = 0; p < PD; ++p) acc += us[p] * A[p * PD + q];
    UA[i * PD + q] = acc;
}

__global__ __launch_bounds__(256) void init_ones_kernel(float* __restrict__ v) {
    v[blockIdx.x * 256 + threadIdx.x] = 1.0f;
}

// ---- coop-loop row dot: K via cached uint4 (immutable), vin via agent-scope
// atomic loads (bypass non-coherent L1/XCD-L2; only 16KB/dot — ~free).
__device__ __forceinline__ float dot_u8_row_a(
    const unsigned char* __restrict__ mrow, const float* vin, int lane)
{
    float acc = 0.f;
    #pragma unroll
    for (int pass = 0; pass < NDIM / (64 * 16); ++pass) {   // 4 passes, 16 u8/lane
        const int j0 = (pass * 64 + lane) * 16;
        const uint4 kv = *(const uint4*)&mrow[j0];
        float b[16];
        #pragma unroll
        for (int e = 0; e < 16; ++e)
            b[e] = __hip_atomic_load(&vin[j0 + e], __ATOMIC_RELAXED,
                                     __HIP_MEMORY_SCOPE_AGENT);
        acc += (float)( kv.x        & 0xffu) * b[0];
        acc += (float)((kv.x >>  8) & 0xffu) * b[1];
        acc += (float)((kv.x >> 16) & 0xffu) * b[2];
        acc += (float)( kv.x >> 24         ) * b[3];
        acc += (float)( kv.y        & 0xffu) * b[4];
        acc += (float)((kv.y >>  8) & 0xffu) * b[5];
        acc += (float)((kv.y >> 16) & 0xffu) * b[6];
        acc += (float)( kv.y >> 24         ) * b[7];
        acc += (float)( kv.z        & 0xffu) * b[8];
        acc += (float)((kv.z >>  8) & 0xffu) * b[9];
        acc += (float)((kv.z >> 16) & 0xffu) * b[10];
        acc += (float)( kv.z >> 24         ) * b[11];
        acc += (float)( kv.w        & 0xffu) * b[12];
        acc += (float)((kv.w >>  8) & 0xffu) * b[13];
        acc += (float)((kv.w >> 16) & 0xffu) * b[14];
        acc += (float)( kv.w >> 24         ) * b[15];
    }
    #pragma unroll
    for (int off = 32; off > 0; off >>= 1) acc += __shfl_down(acc, off, 64);
    return acc;
}

// Persistent Sinkhorn: 512 blocks x 512 threads, one wave per row.
// __launch_bounds__(512,4): min 4 waves/SIMD => VGPR<=128 => 2 blocks/CU
// guaranteed => 512 blocks co-resident (round-11 silent-launch-fail fix).
__global__ __launch_bounds__(512, 4) void sinkhorn_kernel(
    const unsigned char* __restrict__ K8, const unsigned char* __restrict__ KT8,
    const float* __restrict__ mu, const float* __restrict__ nu,
    float* av, float* bv)
{
    cg::grid_group grid = cg::this_grid();
    const int wave = threadIdx.x >> 6;
    const int lane = threadIdx.x & 63;
    const int row  = blockIdx.x * 8 + wave;       // 512*8 = 4096 rows
    const int gtid = blockIdx.x * 512 + threadIdx.x;

    if (gtid < NDIM)
        __hip_atomic_store(&bv[gtid], 1.0f, __ATOMIC_RELEASE,
                           __HIP_MEMORY_SCOPE_AGENT);
    const unsigned char* krow  = K8  + (size_t)row * NDIM;
    const unsigned char* ktrow = KT8 + (size_t)row * NDIM;
    const float mur = mu[row];
    const float nur = nu[row];
    grid.sync();

    for (int it = 0; it < 100; ++it) {
        float acc = dot_u8_row_a(krow, bv, lane);     // 255*(K @ b)
        if (lane == 0)
            __hip_atomic_store(&av[row], 255.0f * mur / acc,
                               __ATOMIC_RELEASE, __HIP_MEMORY_SCOPE_AGENT);
        grid.sync();
        acc = dot_u8_row_a(ktrow, av, lane);          // 255*(K^T @ a)
        if (lane == 0)
            __hip_atomic_store(&bv[row], 255.0f * nur / acc,
                               __ATOMIC_RELEASE, __HIP_MEMORY_SCOPE_AGENT);
        grid.sync();
    }
}

// Fallback loop body (round-8 proven, ~6.8us/dispatch)
__global__ __launch_bounds__(256) void matvec_u8_div_kernel(
    const unsigned char* __restrict__ M, const float* __restrict__ vin,
    const float* __restrict__ num, float* __restrict__ vout)
{
    const int wave = threadIdx.x >> 6;
    const int lane = threadIdx.x & 63;
    const int row  = blockIdx.x * 4 + wave;
    const unsigned char* mrow = M + (size_t)row * NDIM;
    float acc = 0.f;
    #pragma unroll
    for (int pass = 0; pass < NDIM / (64 * 16); ++pass) {
        const int j0 = (pass * 64 + lane) * 16;
        const uint4  kv = *(const uint4*)&mrow[j0];
        const float4 b0 = *(const float4*)&vin[j0];
        const float4 b1 = *(const float4*)&vin[j0 + 4];
        const float4 b2 = *(const float4*)&vin[j0 + 8];
        const float4 b3 = *(const float4*)&vin[j0 + 12];
        acc += (float)( kv.x        & 0xffu) * b0.x;
        acc += (float)((kv.x >>  8) & 0xffu) * b0.y;
        acc += (float)((kv.x >> 16) & 0xffu) * b0.z;
        acc += (float)( kv.x >> 24         ) * b0.w;
        acc += (float)( kv.y        & 0xffu) * b1.x;
        acc += (float)((kv.y >>  8) & 0xffu) * b1.y;
        acc += (float)((kv.y >> 16) & 0xffu) * b1.z;
        acc += (float)( kv.y >> 24         ) * b1.w;
        acc += (float)( kv.z        & 0xffu) * b2.x;
        acc += (float)((kv.z >>  8) & 0xffu) * b2.y;
        acc += (float)((kv.z >> 16) & 0xffu) * b2.z;
        acc += (float)( kv.z >> 24         ) * b2.w;
        acc += (float)( kv.w        & 0xffu) * b3.x;
        acc += (float)((kv.w >>  8) & 0xffu) * b3.y;
        acc += (float)((kv.w >> 16) & 0xffu) * b3.z;
        acc += (float)( kv.w >> 24         ) * b3.w;
    }
    #pragma unroll
    for (int off = 32; off > 0; off >>= 1) acc += __shfl_down(acc, off, 64);
    if (lane == 0) vout[row] = 255.0f * num[row] / acc;
}

// plan via fp32 K32 (round-8 proven, absmax 3.8e-6)
__global__ __launch_bounds__(256) void plan_ew_kernel(
    const float* __restrict__ K32, const float* __restrict__ av,
    const float* __restrict__ bv, float* __restrict__ out)
{
    const size_t base = ((size_t)blockIdx.x * 256 + threadIdx.x) * 4;
    const int i = (int)(base >> 12);
    const int j = (int)(base & 4095);
    const float a = av[i];
    const float4 k4 = *(const float4*)&K32[base];
    const float4 b4 = *(const float4*)&bv[j];
    float4 o;
    o.x = a * k4.x * b4.x;
    o.y = a * k4.y * b4.y;
    o.z = a * k4.z * b4.z;
    o.w = a * k4.w * b4.w;
    *(float4*)&out[base] = o;
}

// fallback plan (ws too small for K32): split-K recompute
__global__ __launch_bounds__(256) void plan_fb_kernel(
    const float* __restrict__ UA, const float* __restrict__ V,
    const float* __restrict__ W, const float* __restrict__ av,
    const float* __restrict__ bv, float* __restrict__ out)
{
    __shared__ float UAs[TS][LDK];
    __shared__ float Vs[TS][LDK];
    const int i0 = blockIdx.y * TS, j0 = blockIdx.x * TS;
    const int t = threadIdx.x;
    const int tx = t & 15, ty = t >> 4;

    float acc[4][4] = {};
    for (int kc = 0; kc < PD; kc += KC) {
        for (int idx = t; idx < TS * (KC / 4); idx += 256) {
            const int r = idx >> 4;
            const int c = (idx & 15) << 2;
            *(float4*)&UAs[r][c] = *(const float4*)&UA[(size_t)(i0 + r) * PD + kc + c];
            *(float4*)&Vs[r][c]  = *(const float4*)&V[(size_t)(j0 + r) * PD + kc + c];
        }
        __syncthreads();
        for (int p = 0; p < KC; p += 4) {
            float4 a4[4], b4[4];
            #pragma unroll
            for (int ii = 0; ii < 4; ++ii) a4[ii] = *(const float4*)&UAs[ty + 16 * ii][p];
            #pragma unroll
            for (int jj = 0; jj < 4; ++jj) b4[jj] = *(const float4*)&Vs[tx + 16 * jj][p];
            #pragma unroll
            for (int ii = 0; ii < 4; ++ii)
                #pragma unroll
                for (int jj = 0; jj < 4; ++jj)
                    acc[ii][jj] += a4[ii].x * b4[jj].x + a4[ii].y * b4[jj].y
                                 + a4[ii].z * b4[jj].z + a4[ii].w * b4[jj].w;
        }
        __syncthreads();
    }

    #pragma unroll
    for (int ii = 0; ii < 4; ++ii) {
        const int i = ty + 16 * ii;
        const float a = av[i0 + i];
        #pragma unroll
        for (int jj = 0; jj < 4; ++jj) {
            const int j = tx + 16 * jj;
            const float w = W[(size_t)(i0 + i) * NDIM + (j0 + j)];
            const float k = 1.0f / (1.0f + expf(w - acc[ii][jj]));
            out[(size_t)(i0 + i) * NDIM + (j0 + j)] = a * k * bv[j0 + j];
        }
    }
}

extern "C" void kernel_launch(void* const* d_in, const int* in_sizes, int n_in,
                              void* d_out, int out_size, void* d_ws, size_t ws_size,
                              hipStream_t stream) {
    const float* U  = (const float*)d_in[0];
    const float* V  = (const float*)d_in[1];
    const float* W  = (const float*)d_in[2];
    const float* mu = (const float*)d_in[3];
    const float* nu = (const float*)d_in[4];
    const float* A  = (const float*)d_in[5];
    float* out = (float*)d_out;

    // Round-8 proven layout: K8/KT8 u8 in d_out (33.5MB <= 64MB, overwritten by
    // plan at the end); K32 fp32 + UA + a/b in ws (66MB, proven present).
    unsigned char* K8  = (unsigned char*)d_out;
    unsigned char* KT8 = K8 + (size_t)NDIM * NDIM;

    const size_t k32_bytes = (size_t)NDIM * NDIM * 4;   // 64MB
    const size_t ua_bytes  = (size_t)NDIM * PD * 4;     // 2MB
    const bool big = ws_size >= k32_bytes + ua_bytes + 3 * NDIM * 4;

    char* ws   = (char*)d_ws;
    float* K32 = big ? (float*)ws : nullptr;
    char*  p   = ws + (big ? k32_bytes : 0);
    float* UA  = (float*)p;
    float* av  = (float*)(p + ua_bytes);
    float* bv  = av + NDIM;

    ua_kernel<<<NDIM, PD, 0, stream>>>(U, A, UA);
    dim3 gridK(NDIM / TS, NDIM / TS);
    buildK_kernel<<<gridK, 256, 0, stream>>>(UA, V, W, K8, KT8, K32);

    void* args[] = { (void*)&K8, (void*)&KT8, (void*)&mu, (void*)&nu,
                     (void*)&av, (void*)&bv };
    hipError_t ce = hipLaunchCooperativeKernel((const void*)sinkhorn_kernel,
                                               dim3(512), dim3(512), args, 0, stream);
    if (ce != hipSuccess) {
        // proven 200-dispatch fallback (~= round-8 perf)
        init_ones_kernel<<<NDIM / 256, 256, 0, stream>>>(bv);
        for (int it = 0; it < 100; ++it) {
            matvec_u8_div_kernel<<<NDIM / 4, 256, 0, stream>>>(K8,  bv, mu, av);
            matvec_u8_div_kernel<<<NDIM / 4, 256, 0, stream>>>(KT8, av, nu, bv);
        }
    }

    if (big) plan_ew_kernel<<<(NDIM / 4) * (NDIM / 256), 256, 0, stream>>>(K32, av, bv, out);
    else     plan_fb_kernel<<<gridK, 256, 0, stream>>>(UA, V, W, av, bv, out);
}

// Round 14
// 22204.445 us; speedup vs baseline: 1.7182x; 1.7182x over previous
//
#include <hip/hip_runtime.h>
#include <hip/hip_cooperative_groups.h>
#include <stdint.h>

namespace cg = cooperative_groups;

#define NDIM 4096
#define PD   128
#define TS   64
#define KC   64          // split-K chunk
#define LDK  (KC + 4)    // LDS row stride (68 floats: bank-skew 4)

// K = sigmoid(UA @ V^T - W): u8 K and K^T (loop) + optional fp32 K32 (plan).
// Round-8/12 proven: ~115us.
__global__ __launch_bounds__(256) void buildK_kernel(
    const float* __restrict__ UA, const float* __restrict__ V,
    const float* __restrict__ W, unsigned char* __restrict__ K8,
    unsigned char* __restrict__ KT8, float* __restrict__ K32)
{
    __shared__ float UAs[TS][LDK];
    __shared__ float Vs[TS][LDK];
    __shared__ float tileT[TS][TS + 1];
    const int i0 = blockIdx.y * TS, j0 = blockIdx.x * TS;
    const int t = threadIdx.x;
    const int tx = t & 15, ty = t >> 4;

    float acc[4][4] = {};
    for (int kc = 0; kc < PD; kc += KC) {
        for (int idx = t; idx < TS * (KC / 4); idx += 256) {
            const int r = idx >> 4;
            const int c = (idx & 15) << 2;
            *(float4*)&UAs[r][c] = *(const float4*)&UA[(size_t)(i0 + r) * PD + kc + c];
            *(float4*)&Vs[r][c]  = *(const float4*)&V[(size_t)(j0 + r) * PD + kc + c];
        }
        __syncthreads();
        for (int p = 0; p < KC; p += 4) {
            float4 a4[4], b4[4];
            #pragma unroll
            for (int ii = 0; ii < 4; ++ii) a4[ii] = *(const float4*)&UAs[ty + 16 * ii][p];
            #pragma unroll
            for (int jj = 0; jj < 4; ++jj) b4[jj] = *(const float4*)&Vs[tx + 16 * jj][p];
            #pragma unroll
            for (int ii = 0; ii < 4; ++ii)
                #pragma unroll
                for (int jj = 0; jj < 4; ++jj)
                    acc[ii][jj] += a4[ii].x * b4[jj].x + a4[ii].y * b4[jj].y
                                 + a4[ii].z * b4[jj].z + a4[ii].w * b4[jj].w;
        }
        __syncthreads();
    }

    #pragma unroll
    for (int ii = 0; ii < 4; ++ii) {
        const int i = ty + 16 * ii;
        #pragma unroll
        for (int jj = 0; jj < 4; ++jj) {
            const int j = tx + 16 * jj;
            const float w = W[(size_t)(i0 + i) * NDIM + (j0 + j)];
            tileT[j][i] = 1.0f / (1.0f + __expf(w - acc[ii][jj])); // sigmoid(UV - W)
        }
    }
    __syncthreads();
    for (int idx = t; idx < TS * TS; idx += 256) {
        const int j = idx >> 6, i = idx & 63;
        KT8[(size_t)(j0 + j) * NDIM + (i0 + i)] = (unsigned char)(tileT[j][i] * 255.f + 0.5f);
    }
    for (int idx = t; idx < TS * TS; idx += 256) {
        const int i = idx >> 6, j = idx & 63;
        const float k = tileT[j][i];
        K8[(size_t)(i0 + i) * NDIM + (j0 + j)] = (unsigned char)(k * 255.f + 0.5f);
        if (K32) K32[(size_t)(i0 + i) * NDIM + (j0 + j)] = k;
    }
}

// UA[i][q] = sum_p U[i][p] * A[p][q]
__global__ __launch_bounds__(128) void ua_kernel(
    const float* __restrict__ U, const float* __restrict__ A, float* __restrict__ UA)
{
    __shared__ float us[PD];
    const int i = blockIdx.x;
    const int q = threadIdx.x;
    us[q] = U[i * PD + q];
    __syncthreads();
    float acc = 0.f;
    #pragma unroll 8
    for (int p = 0; p < PD; ++p) acc += us[p] * A[p * PD + q];
    UA[i * PD + q] = acc;
}

__global__ __launch_bounds__(256) void init_ones_kernel(float* __restrict__ v) {
    v[blockIdx.x * 256 + threadIdx.x] = 1.0f;
}

// 16 u8*f32 FMA terms of one uint4 against 4 float4s (compiler emits v_cvt_f32_ubyteN)
#define ACC16(A, KV, B0, B1, B2, B3)                         \
    A += (float)( (KV).x        & 0xffu) * (B0).x;           \
    A += (float)(((KV).x >>  8) & 0xffu) * (B0).y;           \
    A += (float)(((KV).x >> 16) & 0xffu) * (B0).z;           \
    A += (float)( (KV).x >> 24         ) * (B0).w;           \
    A += (float)( (KV).y        & 0xffu) * (B1).x;           \
    A += (float)(((KV).y >>  8) & 0xffu) * (B1).y;           \
    A += (float)(((KV).y >> 16) & 0xffu) * (B1).z;           \
    A += (float)( (KV).y >> 24         ) * (B1).w;           \
    A += (float)( (KV).z        & 0xffu) * (B2).x;           \
    A += (float)(((KV).z >>  8) & 0xffu) * (B2).y;           \
    A += (float)(((KV).z >> 16) & 0xffu) * (B2).z;           \
    A += (float)( (KV).z >> 24         ) * (B2).w;           \
    A += (float)( (KV).w        & 0xffu) * (B3).x;           \
    A += (float)(((KV).w >>  8) & 0xffu) * (B3).y;           \
    A += (float)(((KV).w >> 16) & 0xffu) * (B3).z;           \
    A += (float)( (KV).w >> 24         ) * (B3).w;

// two-row u8 dot with PLAIN cached loads (round-8-proven access pattern:
// K uint4 fully coalesced; vin float4 L1-resident 16KB). Results on lane 0.
__device__ __forceinline__ void dot2_u8(
    const unsigned char* __restrict__ r0, const unsigned char* __restrict__ r1,
    const float* vin, int lane, float& d0, float& d1)
{
    float a0 = 0.f, a1 = 0.f;
    #pragma unroll
    for (int pass = 0; pass < NDIM / (64 * 16); ++pass) {   // 4 passes, 16 elems/lane
        const int j0 = (pass * 64 + lane) * 16;
        const uint4  ka = *(const uint4*)&r0[j0];
        const uint4  kb = *(const uint4*)&r1[j0];
        const float4 b0 = *(const float4*)&vin[j0];
        const float4 b1 = *(const float4*)&vin[j0 + 4];
        const float4 b2 = *(const float4*)&vin[j0 + 8];
        const float4 b3 = *(const float4*)&vin[j0 + 12];
        ACC16(a0, ka, b0, b1, b2, b3)
        ACC16(a1, kb, b0, b1, b2, b3)
    }
    #pragma unroll
    for (int off = 32; off > 0; off >>= 1) {
        a0 += __shfl_down(a0, off, 64);
        a1 += __shfl_down(a1, off, 64);
    }
    d0 = a0; d1 = a1;
}

// Persistent Sinkhorn: 256 blocks x 512 threads (8 waves), TWO rows per wave
// (halves the vin broadcast traffic and the barrier width vs round 12).
// Writes: agent-scope release atomic stores (r12-proven). Reads: plain cached
// loads; the __threadfence() after each grid.sync() invalidates L1/XCD-L2 so
// fresh values are fetched (r12's per-element atomic loads bypassed ALL caches
// uncoalesced -> 11GB HBM, 40ms — fixed this round).
__global__ __launch_bounds__(512, 4) void sinkhorn_kernel(
    const unsigned char* __restrict__ K8, const unsigned char* __restrict__ KT8,
    const float* __restrict__ mu, const float* __restrict__ nu,
    float* av, float* bv)
{
    cg::grid_group grid = cg::this_grid();
    const int wave = threadIdx.x >> 6;
    const int lane = threadIdx.x & 63;
    const int r0   = blockIdx.x * 16 + wave * 2;  // 256*16 = 4096 rows
    const int r1   = r0 + 1;
    const int gtid = blockIdx.x * 512 + threadIdx.x;

    if (gtid < NDIM)
        __hip_atomic_store(&bv[gtid], 1.0f, __ATOMIC_RELEASE,
                           __HIP_MEMORY_SCOPE_AGENT);
    const unsigned char* k0  = K8  + (size_t)r0 * NDIM;
    const unsigned char* k1  = K8  + (size_t)r1 * NDIM;
    const unsigned char* kt0 = KT8 + (size_t)r0 * NDIM;
    const unsigned char* kt1 = KT8 + (size_t)r1 * NDIM;
    const float mu0 = mu[r0], mu1 = mu[r1];
    const float nu0 = nu[r0], nu1 = nu[r1];
    grid.sync();
    __threadfence();

    float d0, d1;
    for (int it = 0; it < 100; ++it) {
        dot2_u8(k0, k1, bv, lane, d0, d1);            // 255*(K @ b)
        if (lane == 0) {
            __hip_atomic_store(&av[r0], 255.0f * mu0 / d0,
                               __ATOMIC_RELEASE, __HIP_MEMORY_SCOPE_AGENT);
            __hip_atomic_store(&av[r1], 255.0f * mu1 / d1,
                               __ATOMIC_RELEASE, __HIP_MEMORY_SCOPE_AGENT);
        }
        grid.sync();
        __threadfence();
        dot2_u8(kt0, kt1, av, lane, d0, d1);          // 255*(K^T @ a)
        if (lane == 0) {
            __hip_atomic_store(&bv[r0], 255.0f * nu0 / d0,
                               __ATOMIC_RELEASE, __HIP_MEMORY_SCOPE_AGENT);
            __hip_atomic_store(&bv[r1], 255.0f * nu1 / d1,
                               __ATOMIC_RELEASE, __HIP_MEMORY_SCOPE_AGENT);
        }
        grid.sync();
        __threadfence();
    }
}

// Fallback loop body (round-8 proven)
__global__ __launch_bounds__(256) void matvec_u8_div_kernel(
    const unsigned char* __restrict__ M, const float* __restrict__ vin,
    const float* __restrict__ num, float* __restrict__ vout)
{
    const int wave = threadIdx.x >> 6;
    const int lane = threadIdx.x & 63;
    const int row  = blockIdx.x * 4 + wave;
    const unsigned char* mrow = M + (size_t)row * NDIM;
    float acc = 0.f;
    #pragma unroll
    for (int pass = 0; pass < NDIM / (64 * 16); ++pass) {
        const int j0 = (pass * 64 + lane) * 16;
        const uint4  kv = *(const uint4*)&mrow[j0];
        const float4 b0 = *(const float4*)&vin[j0];
        const float4 b1 = *(const float4*)&vin[j0 + 4];
        const float4 b2 = *(const float4*)&vin[j0 + 8];
        const float4 b3 = *(const float4*)&vin[j0 + 12];
        ACC16(acc, kv, b0, b1, b2, b3)
    }
    #pragma unroll
    for (int off = 32; off > 0; off >>= 1) acc += __shfl_down(acc, off, 64);
    if (lane == 0) vout[row] = 255.0f * num[row] / acc;
}

// plan via fp32 K32 (proven, absmax 3.8e-6)
__global__ __launch_bounds__(256) void plan_ew_kernel(
    const float* __restrict__ K32, const float* __restrict__ av,
    const float* __restrict__ bv, float* __restrict__ out)
{
    const size_t base = ((size_t)blockIdx.x * 256 + threadIdx.x) * 4;
    const int i = (int)(base >> 12);
    const int j = (int)(base & 4095);
    const float a = av[i];
    const float4 k4 = *(const float4*)&K32[base];
    const float4 b4 = *(const float4*)&bv[j];
    float4 o;
    o.x = a * k4.x * b4.x;
    o.y = a * k4.y * b4.y;
    o.z = a * k4.z * b4.z;
    o.w = a * k4.w * b4.w;
    *(float4*)&out[base] = o;
}

// fallback plan (ws too small for K32): split-K recompute
__global__ __launch_bounds__(256) void plan_fb_kernel(
    const float* __restrict__ UA, const float* __restrict__ V,
    const float* __restrict__ W, const float* __restrict__ av,
    const float* __restrict__ bv, float* __restrict__ out)
{
    __shared__ float UAs[TS][LDK];
    __shared__ float Vs[TS][LDK];
    const int i0 = blockIdx.y * TS, j0 = blockIdx.x * TS;
    const int t = threadIdx.x;
    const int tx = t & 15, ty = t >> 4;

    float acc[4][4] = {};
    for (int kc = 0; kc < PD; kc += KC) {
        for (int idx = t; idx < TS * (KC / 4); idx += 256) {
            const int r = idx >> 4;
            const int c = (idx & 15) << 2;
            *(float4*)&UAs[r][c] = *(const float4*)&UA[(size_t)(i0 + r) * PD + kc + c];
            *(float4*)&Vs[r][c]  = *(const float4*)&V[(size_t)(j0 + r) * PD + kc + c];
        }
        __syncthreads();
        for (int p = 0; p < KC; p += 4) {
            float4 a4[4], b4[4];
            #pragma unroll
            for (int ii = 0; ii < 4; ++ii) a4[ii] = *(const float4*)&UAs[ty + 16 * ii][p];
            #pragma unroll
            for (int jj = 0; jj < 4; ++jj) b4[jj] = *(const float4*)&Vs[tx + 16 * jj][p];
            #pragma unroll
            for (int ii = 0; ii < 4; ++ii)
                #pragma unroll
                for (int jj = 0; jj < 4; ++jj)
                    acc[ii][jj] += a4[ii].x * b4[jj].x + a4[ii].y * b4[jj].y
                                 + a4[ii].z * b4[jj].z + a4[ii].w * b4[jj].w;
        }
        __syncthreads();
    }

    #pragma unroll
    for (int ii = 0; ii < 4; ++ii) {
        const int i = ty + 16 * ii;
        const float a = av[i0 + i];
        #pragma unroll
        for (int jj = 0; jj < 4; ++jj) {
            const int j = tx + 16 * jj;
            const float w = W[(size_t)(i0 + i) * NDIM + (j0 + j)];
            const float k = 1.0f / (1.0f + expf(w - acc[ii][jj]));
            out[(size_t)(i0 + i) * NDIM + (j0 + j)] = a * k * bv[j0 + j];
        }
    }
}

extern "C" void kernel_launch(void* const* d_in, const int* in_sizes, int n_in,
                              void* d_out, int out_size, void* d_ws, size_t ws_size,
                              hipStream_t stream) {
    const float* U  = (const float*)d_in[0];
    const float* V  = (const float*)d_in[1];
    const float* W  = (const float*)d_in[2];
    const float* mu = (const float*)d_in[3];
    const float* nu = (const float*)d_in[4];
    const float* A  = (const float*)d_in[5];
    float* out = (float*)d_out;

    // K8/KT8 u8 in d_out (33.5MB <= 64MB, overwritten by plan at the end);
    // K32 fp32 + UA + a/b in ws (>=66MB proven by rounds 8/12).
    unsigned char* K8  = (unsigned char*)d_out;
    unsigned char* KT8 = K8 + (size_t)NDIM * NDIM;

    const size_t k32_bytes = (size_t)NDIM * NDIM * 4;   // 64MB
    const size_t ua_bytes  = (size_t)NDIM * PD * 4;     // 2MB
    const bool big = ws_size >= k32_bytes + ua_bytes + 3 * NDIM * 4;

    char* ws   = (char*)d_ws;
    float* K32 = big ? (float*)ws : nullptr;
    char*  p   = ws + (big ? k32_bytes : 0);
    float* UA  = (float*)p;
    float* av  = (float*)(p + ua_bytes);
    float* bv  = av + NDIM;

    ua_kernel<<<NDIM, PD, 0, stream>>>(U, A, UA);
    dim3 gridK(NDIM / TS, NDIM / TS);
    buildK_kernel<<<gridK, 256, 0, stream>>>(UA, V, W, K8, KT8, K32);

    void* args[] = { (void*)&K8, (void*)&KT8, (void*)&mu, (void*)&nu,
                     (void*)&av, (void*)&bv };
    hipError_t ce = hipLaunchCooperativeKernel((const void*)sinkhorn_kernel,
                                               dim3(256), dim3(512), args, 0, stream);
    if (ce != hipSuccess) {
        // proven 200-dispatch fallback (~= round-8 perf)
        init_ones_kernel<<<NDIM / 256, 256, 0, stream>>>(bv);
        for (int it = 0; it < 100; ++it) {
            matvec_u8_div_kernel<<<NDIM / 4, 256, 0, stream>>>(K8,  bv, mu, av);
            matvec_u8_div_kernel<<<NDIM / 4, 256, 0, stream>>>(KT8, av, nu, bv);
        }
    }

    if (big) plan_ew_kernel<<<(NDIM / 4) * (NDIM / 256), 256, 0, stream>>>(K32, av, bv, out);
    else     plan_fb_kernel<<<gridK, 256, 0, stream>>>(UA, V, W, av, bv, out);
}

// Round 15
// 17116.000 us; speedup vs baseline: 2.2290x; 1.2973x over previous
//
#include <hip/hip_runtime.h>
#include <hip/hip_cooperative_groups.h>
#include <stdint.h>

namespace cg = cooperative_groups;

#define NDIM 4096
#define PD   128
#define TS   64
#define KC   64          // split-K chunk
#define LDK  (KC + 4)    // LDS row stride (68 floats: bank-skew 4)

// K = sigmoid(UA @ V^T - W): u8 K and K^T (loop) + optional fp32 K32 (plan).
// Round-8/12 proven: ~115us.
__global__ __launch_bounds__(256) void buildK_kernel(
    const float* __restrict__ UA, const float* __restrict__ V,
    const float* __restrict__ W, unsigned char* __restrict__ K8,
    unsigned char* __restrict__ KT8, float* __restrict__ K32)
{
    __shared__ float UAs[TS][LDK];
    __shared__ float Vs[TS][LDK];
    __shared__ float tileT[TS][TS + 1];
    const int i0 = blockIdx.y * TS, j0 = blockIdx.x * TS;
    const int t = threadIdx.x;
    const int tx = t & 15, ty = t >> 4;

    float acc[4][4] = {};
    for (int kc = 0; kc < PD; kc += KC) {
        for (int idx = t; idx < TS * (KC / 4); idx += 256) {
            const int r = idx >> 4;
            const int c = (idx & 15) << 2;
            *(float4*)&UAs[r][c] = *(const float4*)&UA[(size_t)(i0 + r) * PD + kc + c];
            *(float4*)&Vs[r][c]  = *(const float4*)&V[(size_t)(j0 + r) * PD + kc + c];
        }
        __syncthreads();
        for (int p = 0; p < KC; p += 4) {
            float4 a4[4], b4[4];
            #pragma unroll
            for (int ii = 0; ii < 4; ++ii) a4[ii] = *(const float4*)&UAs[ty + 16 * ii][p];
            #pragma unroll
            for (int jj = 0; jj < 4; ++jj) b4[jj] = *(const float4*)&Vs[tx + 16 * jj][p];
            #pragma unroll
            for (int ii = 0; ii < 4; ++ii)
                #pragma unroll
                for (int jj = 0; jj < 4; ++jj)
                    acc[ii][jj] += a4[ii].x * b4[jj].x + a4[ii].y * b4[jj].y
                                 + a4[ii].z * b4[jj].z + a4[ii].w * b4[jj].w;
        }
        __syncthreads();
    }

    #pragma unroll
    for (int ii = 0; ii < 4; ++ii) {
        const int i = ty + 16 * ii;
        #pragma unroll
        for (int jj = 0; jj < 4; ++jj) {
            const int j = tx + 16 * jj;
            const float w = W[(size_t)(i0 + i) * NDIM + (j0 + j)];
            tileT[j][i] = 1.0f / (1.0f + __expf(w - acc[ii][jj])); // sigmoid(UV - W)
        }
    }
    __syncthreads();
    for (int idx = t; idx < TS * TS; idx += 256) {
        const int j = idx >> 6, i = idx & 63;
        KT8[(size_t)(j0 + j) * NDIM + (i0 + i)] = (unsigned char)(tileT[j][i] * 255.f + 0.5f);
    }
    for (int idx = t; idx < TS * TS; idx += 256) {
        const int i = idx >> 6, j = idx & 63;
        const float k = tileT[j][i];
        K8[(size_t)(i0 + i) * NDIM + (j0 + j)] = (unsigned char)(k * 255.f + 0.5f);
        if (K32) K32[(size_t)(i0 + i) * NDIM + (j0 + j)] = k;
    }
}

// UA[i][q] = sum_p U[i][p] * A[p][q]
__global__ __launch_bounds__(128) void ua_kernel(
    const float* __restrict__ U, const float* __restrict__ A, float* __restrict__ UA)
{
    __shared__ float us[PD];
    const int i = blockIdx.x;
    const int q = threadIdx.x;
    us[q] = U[i * PD + q];
    __syncthreads();
    float acc = 0.f;
    #pragma unroll 8
    for (int p = 0; p < PD; ++p) acc += us[p] * A[p * PD + q];
    UA[i * PD + q] = acc;
}

__global__ __launch_bounds__(256) void init_ones_kernel(float* __restrict__ v) {
    v[blockIdx.x * 256 + threadIdx.x] = 1.0f;
}

// 16 u8*f32 terms of one uint4 vs 4 float4s (fallback kernel only)
#define ACC16(A, KV, B0, B1, B2, B3)                         \
    A += (float)( (KV).x        & 0xffu) * (B0).x;           \
    A += (float)(((KV).x >>  8) & 0xffu) * (B0).y;           \
    A += (float)(((KV).x >> 16) & 0xffu) * (B0).z;           \
    A += (float)( (KV).x >> 24         ) * (B0).w;           \
    A += (float)( (KV).y        & 0xffu) * (B1).x;           \
    A += (float)(((KV).y >>  8) & 0xffu) * (B1).y;           \
    A += (float)(((KV).y >> 16) & 0xffu) * (B1).z;           \
    A += (float)( (KV).y >> 24         ) * (B1).w;           \
    A += (float)( (KV).z        & 0xffu) * (B2).x;           \
    A += (float)(((KV).z >>  8) & 0xffu) * (B2).y;           \
    A += (float)(((KV).z >> 16) & 0xffu) * (B2).z;           \
    A += (float)( (KV).z >> 24         ) * (B2).w;           \
    A += (float)( (KV).w        & 0xffu) * (B3).x;           \
    A += (float)(((KV).w >>  8) & 0xffu) * (B3).y;           \
    A += (float)(((KV).w >> 16) & 0xffu) * (B3).z;           \
    A += (float)( (KV).w >> 24         ) * (B3).w;

// Persistent Sinkhorn, round-15 memory model:
//  - K8/KT8: IMMUTABLE -> plain cached loads, NO fences ever. Per-XCD slice
//    (32 blocks x 128KB) ~= 4MB L2 -> L2-resident across iterations.
//    (r14's __threadfence() evicted K every half-iter -> 4.28GB refetch, 22ms.)
//  - a/b: staged into LDS once per half-iter via COALESCED agent-scope relaxed
//    atomic loads (r12-proven coherent primitive, but 4B/lane consecutive —
//    not r12's 64-lines-per-instruction scatter). Dots read LDS.
//  - dot mapping: 4 elems/lane/pass -> u32 K loads (256B/wave coalesced),
//    ds_read_b128 at lane-stride 16B = standard conflict-free LDS pattern.
//  - writes: agent-release atomic stores (r12/r14-proven).
__global__ __launch_bounds__(512, 4) void sinkhorn_kernel(
    const unsigned char* __restrict__ K8, const unsigned char* __restrict__ KT8,
    const float* __restrict__ mu, const float* __restrict__ nu,
    float* av, float* bv)
{
    cg::grid_group grid = cg::this_grid();
    __shared__ float vlds[NDIM];                  // 16KB
    const int t    = threadIdx.x;
    const int wave = t >> 6;
    const int lane = t & 63;
    const int r0   = blockIdx.x * 16 + wave * 2;  // 256 blocks * 16 rows = 4096
    const int r1   = r0 + 1;
    const int gtid = blockIdx.x * 512 + t;

    if (gtid < NDIM)
        __hip_atomic_store(&bv[gtid], 1.0f, __ATOMIC_RELEASE,
                           __HIP_MEMORY_SCOPE_AGENT);
    const unsigned char* k0  = K8  + (size_t)r0 * NDIM;
    const unsigned char* k1  = K8  + (size_t)r1 * NDIM;
    const unsigned char* kt0 = KT8 + (size_t)r0 * NDIM;
    const unsigned char* kt1 = KT8 + (size_t)r1 * NDIM;
    const float mu0 = mu[r0], mu1 = mu[r1];
    const float nu0 = nu[r0], nu1 = nu[r1];
    grid.sync();

    for (int it = 0; it < 100; ++it) {
        // ---- phase A: a = 255*mu / (K @ b) ----
        #pragma unroll
        for (int k = 0; k < NDIM / 512; ++k)      // 8 coalesced coherent loads
            vlds[t + k * 512] = __hip_atomic_load(&bv[t + k * 512],
                                   __ATOMIC_RELAXED, __HIP_MEMORY_SCOPE_AGENT);
        __syncthreads();
        {
            float a0 = 0.f, a1 = 0.f;
            #pragma unroll
            for (int pass = 0; pass < 16; ++pass) {
                const int e0 = pass * 256 + lane * 4;
                const uint32_t ka = *(const uint32_t*)&k0[e0];
                const uint32_t kb = *(const uint32_t*)&k1[e0];
                const float4   b  = *(const float4*)&vlds[e0];
                a0 += (float)( ka        & 0xffu) * b.x;
                a0 += (float)((ka >>  8) & 0xffu) * b.y;
                a0 += (float)((ka >> 16) & 0xffu) * b.z;
                a0 += (float)( ka >> 24         ) * b.w;
                a1 += (float)( kb        & 0xffu) * b.x;
                a1 += (float)((kb >>  8) & 0xffu) * b.y;
                a1 += (float)((kb >> 16) & 0xffu) * b.z;
                a1 += (float)( kb >> 24         ) * b.w;
            }
            #pragma unroll
            for (int off = 32; off > 0; off >>= 1) {
                a0 += __shfl_down(a0, off, 64);
                a1 += __shfl_down(a1, off, 64);
            }
            if (lane == 0) {
                __hip_atomic_store(&av[r0], 255.0f * mu0 / a0,
                                   __ATOMIC_RELEASE, __HIP_MEMORY_SCOPE_AGENT);
                __hip_atomic_store(&av[r1], 255.0f * mu1 / a1,
                                   __ATOMIC_RELEASE, __HIP_MEMORY_SCOPE_AGENT);
            }
        }
        grid.sync();

        // ---- phase B: b = 255*nu / (K^T @ a) ----
        #pragma unroll
        for (int k = 0; k < NDIM / 512; ++k)
            vlds[t + k * 512] = __hip_atomic_load(&av[t + k * 512],
                                   __ATOMIC_RELAXED, __HIP_MEMORY_SCOPE_AGENT);
        __syncthreads();
        {
            float a0 = 0.f, a1 = 0.f;
            #pragma unroll
            for (int pass = 0; pass < 16; ++pass) {
                const int e0 = pass * 256 + lane * 4;
                const uint32_t ka = *(const uint32_t*)&kt0[e0];
                const uint32_t kb = *(const uint32_t*)&kt1[e0];
                const float4   b  = *(const float4*)&vlds[e0];
                a0 += (float)( ka        & 0xffu) * b.x;
                a0 += (float)((ka >>  8) & 0xffu) * b.y;
                a0 += (float)((ka >> 16) & 0xffu) * b.z;
                a0 += (float)( ka >> 24         ) * b.w;
                a1 += (float)( kb        & 0xffu) * b.x;
                a1 += (float)((kb >>  8) & 0xffu) * b.y;
                a1 += (float)((kb >> 16) & 0xffu) * b.z;
                a1 += (float)( kb >> 24         ) * b.w;
            }
            #pragma unroll
            for (int off = 32; off > 0; off >>= 1) {
                a0 += __shfl_down(a0, off, 64);
                a1 += __shfl_down(a1, off, 64);
            }
            if (lane == 0) {
                __hip_atomic_store(&bv[r0], 255.0f * nu0 / a0,
                                   __ATOMIC_RELEASE, __HIP_MEMORY_SCOPE_AGENT);
                __hip_atomic_store(&bv[r1], 255.0f * nu1 / a1,
                                   __ATOMIC_RELEASE, __HIP_MEMORY_SCOPE_AGENT);
            }
        }
        grid.sync();
    }
}

// Fallback loop body (round-8 proven)
__global__ __launch_bounds__(256) void matvec_u8_div_kernel(
    const unsigned char* __restrict__ M, const float* __restrict__ vin,
    const float* __restrict__ num, float* __restrict__ vout)
{
    const int wave = threadIdx.x >> 6;
    const int lane = threadIdx.x & 63;
    const int row  = blockIdx.x * 4 + wave;
    const unsigned char* mrow = M + (size_t)row * NDIM;
    float acc = 0.f;
    #pragma unroll
    for (int pass = 0; pass < NDIM / (64 * 16); ++pass) {
        const int j0 = (pass * 64 + lane) * 16;
        const uint4  kv = *(const uint4*)&mrow[j0];
        const float4 b0 = *(const float4*)&vin[j0];
        const float4 b1 = *(const float4*)&vin[j0 + 4];
        const float4 b2 = *(const float4*)&vin[j0 + 8];
        const float4 b3 = *(const float4*)&vin[j0 + 12];
        ACC16(acc, kv, b0, b1, b2, b3)
    }
    #pragma unroll
    for (int off = 32; off > 0; off >>= 1) acc += __shfl_down(acc, off, 64);
    if (lane == 0) vout[row] = 255.0f * num[row] / acc;
}

// plan via fp32 K32 (proven, absmax 3.8e-6)
__global__ __launch_bounds__(256) void plan_ew_kernel(
    const float* __restrict__ K32, const float* __restrict__ av,
    const float* __restrict__ bv, float* __restrict__ out)
{
    const size_t base = ((size_t)blockIdx.x * 256 + threadIdx.x) * 4;
    const int i = (int)(base >> 12);
    const int j = (int)(base & 4095);
    const float a = av[i];
    const float4 k4 = *(const float4*)&K32[base];
    const float4 b4 = *(const float4*)&bv[j];
    float4 o;
    o.x = a * k4.x * b4.x;
    o.y = a * k4.y * b4.y;
    o.z = a * k4.z * b4.z;
    o.w = a * k4.w * b4.w;
    *(float4*)&out[base] = o;
}

// fallback plan (ws too small for K32): split-K recompute
__global__ __launch_bounds__(256) void plan_fb_kernel(
    const float* __restrict__ UA, const float* __restrict__ V,
    const float* __restrict__ W, const float* __restrict__ av,
    const float* __restrict__ bv, float* __restrict__ out)
{
    __shared__ float UAs[TS][LDK];
    __shared__ float Vs[TS][LDK];
    const int i0 = blockIdx.y * TS, j0 = blockIdx.x * TS;
    const int t = threadIdx.x;
    const int tx = t & 15, ty = t >> 4;

    float acc[4][4] = {};
    for (int kc = 0; kc < PD; kc += KC) {
        for (int idx = t; idx < TS * (KC / 4); idx += 256) {
            const int r = idx >> 4;
            const int c = (idx & 15) << 2;
            *(float4*)&UAs[r][c] = *(const float4*)&UA[(size_t)(i0 + r) * PD + kc + c];
            *(float4*)&Vs[r][c]  = *(const float4*)&V[(size_t)(j0 + r) * PD + kc + c];
        }
        __syncthreads();
        for (int p = 0; p < KC; p += 4) {
            float4 a4[4], b4[4];
            #pragma unroll
            for (int ii = 0; ii < 4; ++ii) a4[ii] = *(const float4*)&UAs[ty + 16 * ii][p];
            #pragma unroll
            for (int jj = 0; jj < 4; ++jj) b4[jj] = *(const float4*)&Vs[tx + 16 * jj][p];
            #pragma unroll
            for (int ii = 0; ii < 4; ++ii)
                #pragma unroll
                for (int jj = 0; jj < 4; ++jj)
                    acc[ii][jj] += a4[ii].x * b4[jj].x + a4[ii].y * b4[jj].y
                                 + a4[ii].z * b4[jj].z + a4[ii].w * b4[jj].w;
        }
        __syncthreads();
    }

    #pragma unroll
    for (int ii = 0; ii < 4; ++ii) {
        const int i = ty + 16 * ii;
        const float a = av[i0 + i];
        #pragma unroll
        for (int jj = 0; jj < 4; ++jj) {
            const int j = tx + 16 * jj;
            const float w = W[(size_t)(i0 + i) * NDIM + (j0 + j)];
            const float k = 1.0f / (1.0f + expf(w - acc[ii][jj]));
            out[(size_t)(i0 + i) * NDIM + (j0 + j)] = a * k * bv[j0 + j];
        }
    }
}

extern "C" void kernel_launch(void* const* d_in, const int* in_sizes, int n_in,
                              void* d_out, int out_size, void* d_ws, size_t ws_size,
                              hipStream_t stream) {
    const float* U  = (const float*)d_in[0];
    const float* V  = (const float*)d_in[1];
    const float* W  = (const float*)d_in[2];
    const float* mu = (const float*)d_in[3];
    const float* nu = (const float*)d_in[4];
    const float* A  = (const float*)d_in[5];
    float* out = (float*)d_out;

    // K8/KT8 u8 in d_out (33.5MB <= 64MB, overwritten by plan at the end);
    // K32 fp32 + UA + a/b in ws (>=66MB proven by rounds 8/12).
    unsigned char* K8  = (unsigned char*)d_out;
    unsigned char* KT8 = K8 + (size_t)NDIM * NDIM;

    const size_t k32_bytes = (size_t)NDIM * NDIM * 4;   // 64MB
    const size_t ua_bytes  = (size_t)NDIM * PD * 4;     // 2MB
    const bool big = ws_size >= k32_bytes + ua_bytes + 3 * NDIM * 4;

    char* ws   = (char*)d_ws;
    float* K32 = big ? (float*)ws : nullptr;
    char*  p   = ws + (big ? k32_bytes : 0);
    float* UA  = (float*)p;
    float* av  = (float*)(p + ua_bytes);
    float* bv  = av + NDIM;

    ua_kernel<<<NDIM, PD, 0, stream>>>(U, A, UA);
    dim3 gridK(NDIM / TS, NDIM / TS);
    buildK_kernel<<<gridK, 256, 0, stream>>>(UA, V, W, K8, KT8, K32);

    void* args[] = { (void*)&K8, (void*)&KT8, (void*)&mu, (void*)&nu,
                     (void*)&av, (void*)&bv };
    hipError_t ce = hipLaunchCooperativeKernel((const void*)sinkhorn_kernel,
                                               dim3(256), dim3(512), args, 0, stream);
    if (ce != hipSuccess) {
        // proven 200-dispatch fallback (~= round-8 perf)
        init_ones_kernel<<<NDIM / 256, 256, 0, stream>>>(bv);
        for (int it = 0; it < 100; ++it) {
            matvec_u8_div_kernel<<<NDIM / 4, 256, 0, stream>>>(K8,  bv, mu, av);
            matvec_u8_div_kernel<<<NDIM / 4, 256, 0, stream>>>(KT8, av, nu, bv);
        }
    }

    if (big) plan_ew_kernel<<<(NDIM / 4) * (NDIM / 256), 256, 0, stream>>>(K32, av, bv, out);
    else     plan_fb_kernel<<<gridK, 256, 0, stream>>>(UA, V, W, av, bv, out);
}